// Round 5
// baseline (380.962 us; speedup 1.0000x reference)
//
#include <hip/hip_runtime.h>
#include <cmath>

// Problem constants (fixed by the reference)
constexpr int TOT = 131072;   // 32 graphs * 4096 nodes
constexpr int NE  = 1048576;  // edges
constexpr int NMASK = 4095;   // N-1, N=4096

typedef __attribute__((ext_vector_type(8))) short bf16x8;
typedef __attribute__((ext_vector_type(4))) float f32x4;

// ---- bf16 helpers (RNE) ----
__device__ inline float bf2f(unsigned int u16) {
    union { unsigned int i; float f; } x; x.i = u16 << 16; return x.f;
}
__device__ inline unsigned short f2bf(float f) {
    union { float f; unsigned int i; } x; x.f = f;
    unsigned int r = (x.i + 0x7fffu + ((x.i >> 16) & 1u)) >> 16;
    return (unsigned short)r;
}
__device__ inline void unpack8(uint4 v, float* f) {
    f[0] = bf2f(v.x & 0xffffu); f[1] = bf2f(v.x >> 16);
    f[2] = bf2f(v.y & 0xffffu); f[3] = bf2f(v.y >> 16);
    f[4] = bf2f(v.z & 0xffffu); f[5] = bf2f(v.z >> 16);
    f[6] = bf2f(v.w & 0xffffu); f[7] = bf2f(v.w >> 16);
}
__device__ inline uint4 pack8(const float* f) {
    uint4 v;
    v.x = (unsigned)f2bf(f[0]) | ((unsigned)f2bf(f[1]) << 16);
    v.y = (unsigned)f2bf(f[2]) | ((unsigned)f2bf(f[3]) << 16);
    v.z = (unsigned)f2bf(f[4]) | ((unsigned)f2bf(f[5]) << 16);
    v.w = (unsigned)f2bf(f[6]) | ((unsigned)f2bf(f[7]) << 16);
    return v;
}

// ================= adjacency build: per-dst linked list =================
// 8 edges per thread -> 8 independent atomicExch in flight (k_link was
// latency-bound at 1 dependent atomic/thread: 45 us @ 22 G/s in round 4).
__global__ __launch_bounds__(256) void k_link(const int* __restrict__ src,
                                              const int* __restrict__ dst,
                                              int* __restrict__ head,
                                              int2* __restrict__ nodes) {
    int t = blockIdx.x * 256 + threadIdx.x;   // 512 blocks * 256 = 131072 threads
#pragma unroll
    for (int i = 0; i < 8; ++i) {
        int e = t + i * 131072;
        int d = dst[e];
        int old = atomicExch(&head[d], e);
        nodes[e] = make_int2(src[e], old);
    }
}

// fused: chain-walk degree -> dinv, and xs = x*dinv -> bf16 (64 ch).
// t = row*8 + g; all 8 lanes of a row walk the same chain (broadcast loads).
__global__ __launch_bounds__(256) void k_prep(const float4* __restrict__ x,
                                              const int* __restrict__ head,
                                              const int2* __restrict__ nodes,
                                              float* __restrict__ dinv,
                                              uint4* __restrict__ out) {
    int t = blockIdx.x * 256 + threadIdx.x;   // t < TOT*8
    int d = t >> 3;
    int c = 0;
    int e = head[d];
    while (e >= 0) { ++c; e = nodes[e].y; }
    float dv = rsqrtf((float)c + 1.0f);       // +1 self-loop
    if ((t & 7) == 0) dinv[d] = dv;
    float4 v0 = x[t * 2], v1 = x[t * 2 + 1];
    float f[8] = { v0.x * dv, v0.y * dv, v0.z * dv, v0.w * dv,
                   v1.x * dv, v1.y * dv, v1.z * dv, v1.w * dv };
    out[t] = pack8(f);
}

// ================= weight packing into MFMA B-fragment order =================
// reader: lane reads wp[((kc*NT + nt)*64 + lane)*8 + j] = W[kc*32+(lane>>4)*8+j][nt*16+(lane&15)]
// taps==1: W row-major [K][COUT]; taps==3: original conv w[COUT][CIN][3], k = t*CIN + c.
__global__ __launch_bounds__(256) void k_packall(
    const float* __restrict__ W1, const float* __restrict__ W2, const float* __restrict__ W3,
    const float* __restrict__ tW1, const float* __restrict__ tW2, const float* __restrict__ tW3,
    unsigned short* __restrict__ g1, unsigned short* __restrict__ g2, unsigned short* __restrict__ g3,
    unsigned short* __restrict__ c1, unsigned short* __restrict__ c2, unsigned short* __restrict__ c3) {
    int gid = blockIdx.x * 256 + threadIdx.x;
    const float* w; unsigned short* wp; int CIN, COUT, taps, idx;
    if      (gid <  8192) { w = W1;  wp = g1; CIN = 64;  COUT = 128; taps = 1; idx = gid; }
    else if (gid < 12288) { w = W2;  wp = g2; CIN = 128; COUT = 32;  taps = 1; idx = gid - 8192; }
    else if (gid < 16384) { w = W3;  wp = g3; CIN = 32;  COUT = 128; taps = 1; idx = gid - 12288; }
    else if (gid < 65536) { w = tW1; wp = c1; CIN = 128; COUT = 128; taps = 3; idx = gid - 16384; }
    else if (gid < 77824) { w = tW2; wp = c2; CIN = 128; COUT = 32;  taps = 3; idx = gid - 65536; }
    else if (gid < 90112) { w = tW3; wp = c3; CIN = 32;  COUT = 128; taps = 3; idx = gid - 77824; }
    else return;
    int j = idx & 7;
    int L = (idx >> 3) & 63;
    int f = idx >> 9;
    int NT = COUT >> 4;
    int kc = f / NT, nt = f - kc * NT;
    int k = kc * 32 + (L >> 4) * 8 + j;
    int n = nt * 16 + (L & 15);
    float v;
    if (taps == 1) v = w[k * COUT + n];
    else { int t = k / CIN, c = k - t * CIN; v = w[(n * CIN + c) * 3 + t]; }
    wp[idx] = f2bf(v);
}

// ================= linked-list gather =================
// EPI==2: out = acc * dinv[d]                (pre-scale for the following GEMM)
// EPI==1: out = relu(acc*dinv + bias)*dinv   (layer-2 epilogue)
template<int LC, int EPI>
__global__ __launch_bounds__(256) void k_gatherb(const uint4* __restrict__ xs,
                                                 const int* __restrict__ head,
                                                 const int2* __restrict__ nodes,
                                                 const float* __restrict__ dinv,
                                                 const float* __restrict__ bias,
                                                 uint4* __restrict__ out) {
    int t = blockIdx.x * 256 + threadIdx.x;   // t < TOT << LC
    int d = t >> LC;
    int g = t & ((1 << LC) - 1);
    float a[8];
    unpack8(xs[t], a);                        // self-loop term
    int e = head[d];
    while (e >= 0) {
        int2 nd = nodes[e];                   // {src, next} in one 8B load
        float f[8];
        unpack8(xs[(nd.x << LC) + g], f);
#pragma unroll
        for (int j = 0; j < 8; ++j) a[j] += f[j];
        e = nd.y;
    }
    float dv = dinv[d];
    if (EPI == 1) {
#pragma unroll
        for (int j = 0; j < 8; ++j)
            a[j] = fmaxf(fmaf(a[j], dv, bias[g * 8 + j]), 0.0f) * dv;
    } else {
#pragma unroll
        for (int j = 0; j < 8; ++j) a[j] *= dv;
    }
    out[t] = pack8(a);
}

// ================= MFMA dense / conv1d =================
template<int CIN, int COUT, int TAPS, bool RELU, bool BIAS, bool SOUT>
__global__ __launch_bounds__(256) void k_mm(const unsigned short* __restrict__ x,
                                            const bf16x8* __restrict__ wp,
                                            const float* __restrict__ bias,
                                            const float* __restrict__ dinv,
                                            unsigned short* __restrict__ y) {
    constexpr int ROWS = 64;
    constexpr int HALO = (TAPS == 3) ? 1 : 0;
    constexpr int TR = ROWS + 2 * HALO;
    constexpr int SC = CIN + 8;
    constexpr int NCH = CIN / 32;
    constexpr int NK = TAPS * NCH;
    constexpr int NT = COUT / 16;
    constexpr int WN = (COUT == 128) ? 2 : 1;
    constexpr int WM = (COUT == 128) ? 4 : 2;
    __shared__ __attribute__((aligned(16))) unsigned short tile[TR * SC];

    const int R0 = blockIdx.x * ROWS;
    const int n0 = R0 & NMASK; (void)n0;

    constexpr int NLD = TR * (CIN / 8);
    for (int idx = threadIdx.x; idx < NLD; idx += 256) {
        int tr = idx / (CIN / 8);
        int c8 = idx - tr * (CIN / 8);
        int ro = tr - HALO;
        bool valid = true;
        if (TAPS == 3) {
            if (ro < 0) valid = (n0 > 0);
            else if (ro >= ROWS) valid = (n0 + ROWS < 4096);
        }
        uint4 v = make_uint4(0, 0, 0, 0);
        if (valid) v = *(const uint4*)(x + (long)(R0 + ro) * CIN + c8 * 8);
        *(uint4*)(tile + tr * SC + c8 * 8) = v;
    }
    __syncthreads();

    const int lane = threadIdx.x & 63;
    const int w = threadIdx.x >> 6;
    const int l16 = lane & 15;
    const int q = lane >> 4;
    const int colbase = (COUT == 128) ? w * 32 : (w & 1) * 16;
    const int rowbase = (COUT == 128) ? 0 : (w >> 1) * 32;
    const int nt0 = colbase >> 4;

    f32x4 acc[WM][WN];
#pragma unroll
    for (int wm = 0; wm < WM; ++wm)
#pragma unroll
        for (int nt = 0; nt < WN; ++nt) acc[wm][nt] = (f32x4){0.f, 0.f, 0.f, 0.f};

    const bf16x8* __restrict__ wpl = wp + lane;

#pragma unroll
    for (int kc = 0; kc < NK; ++kc) {
        const int tap = (TAPS == 3) ? (kc / NCH) : 0;
        const int ch  = (TAPS == 3) ? (kc - tap * NCH) : kc;
        bf16x8 a[WM];
#pragma unroll
        for (int wm = 0; wm < WM; ++wm)
            a[wm] = *(const bf16x8*)(tile + (rowbase + wm * 16 + l16 + tap) * SC + ch * 32 + q * 8);
        bf16x8 b[WN];
#pragma unroll
        for (int nt = 0; nt < WN; ++nt)
            b[nt] = wpl[(kc * NT + nt0 + nt) * 64];
#pragma unroll
        for (int wm = 0; wm < WM; ++wm)
#pragma unroll
            for (int nt = 0; nt < WN; ++nt)
                acc[wm][nt] = __builtin_amdgcn_mfma_f32_16x16x32_bf16(a[wm], b[nt], acc[wm][nt], 0, 0, 0);
    }

    // epilogue: C/D layout col=lane&15, row=q*4+reg
#pragma unroll
    for (int wm = 0; wm < WM; ++wm) {
#pragma unroll
        for (int nt = 0; nt < WN; ++nt) {
            int col = colbase + nt * 16 + l16;
            float bi = BIAS ? bias[col] : 0.0f;
#pragma unroll
            for (int r = 0; r < 4; ++r) {
                int row = R0 + rowbase + wm * 16 + q * 4 + r;
                float v = acc[wm][nt][r] + bi;
                if (RELU) v = fmaxf(v, 0.0f);
                if (SOUT) v *= dinv[row];
                y[(long)row * COUT + col] = f2bf(v);
            }
        }
    }
}

// ================= fused conv3 (32->128, k=3) + heads =================
// xt = relu(conv(X) + tb3); pi/nb/p = act(xt @ W? + b?). xt never hits HBM:
// per-wave accumulators hold a 64x32 slab of xt; shfl-tree over l16 reduces
// the 32-col partial dot, LDS reduces across the 4 waves.
__global__ __launch_bounds__(256) void k_conv_heads(
    const unsigned short* __restrict__ x, const bf16x8* __restrict__ wp,
    const float* __restrict__ bias,
    const float* __restrict__ Wpi, const float* __restrict__ bpi,
    const float* __restrict__ Wn,  const float* __restrict__ bn,
    const float* __restrict__ Wp,  const float* __restrict__ bp,
    float* __restrict__ out) {
    constexpr int CIN = 32, TAPS = 3;
    constexpr int ROWS = 64, HALO = 1, TR = 66, SC = CIN + 8;
    constexpr int NK = 3, NT = 8, WN = 2, WM = 4;
    __shared__ __attribute__((aligned(16))) unsigned short tile[TR * SC];
    __shared__ float part[4][3][64];

    const int R0 = blockIdx.x * ROWS;
    const int n0 = R0 & NMASK;

    constexpr int NLD = TR * (CIN / 8);
    for (int idx = threadIdx.x; idx < NLD; idx += 256) {
        int tr = idx / (CIN / 8);
        int c8 = idx - tr * (CIN / 8);
        int ro = tr - HALO;
        bool valid = true;
        if (ro < 0) valid = (n0 > 0);
        else if (ro >= ROWS) valid = (n0 + ROWS < 4096);
        uint4 v = make_uint4(0, 0, 0, 0);
        if (valid) v = *(const uint4*)(x + (long)(R0 + ro) * CIN + c8 * 8);
        *(uint4*)(tile + tr * SC + c8 * 8) = v;
    }
    __syncthreads();

    const int lane = threadIdx.x & 63;
    const int w = threadIdx.x >> 6;
    const int l16 = lane & 15;
    const int q = lane >> 4;
    const int colbase = w * 32;
    const int nt0 = colbase >> 4;

    f32x4 acc[WM][WN];
#pragma unroll
    for (int wm = 0; wm < WM; ++wm)
#pragma unroll
        for (int nt = 0; nt < WN; ++nt) acc[wm][nt] = (f32x4){0.f, 0.f, 0.f, 0.f};

    const bf16x8* __restrict__ wpl = wp + lane;

#pragma unroll
    for (int kc = 0; kc < NK; ++kc) {
        bf16x8 a[WM];
#pragma unroll
        for (int wm = 0; wm < WM; ++wm)
            a[wm] = *(const bf16x8*)(tile + (wm * 16 + l16 + kc) * SC + q * 8);
        bf16x8 b[WN];
#pragma unroll
        for (int nt = 0; nt < WN; ++nt)
            b[nt] = wpl[(kc * NT + nt0 + nt) * 64];
#pragma unroll
        for (int wm = 0; wm < WM; ++wm)
#pragma unroll
            for (int nt = 0; nt < WN; ++nt)
                acc[wm][nt] = __builtin_amdgcn_mfma_f32_16x16x32_bf16(a[wm], b[nt], acc[wm][nt], 0, 0, 0);
    }

    // heads epilogue
    const int col0 = colbase + l16, col1 = colbase + 16 + l16;
    const float b0 = bias[col0], b1 = bias[col1];
    const float wpi0 = Wpi[col0], wpi1 = Wpi[col1];
    const float wn0  = Wn[col0],  wn1  = Wn[col1];
    const float wq0  = Wp[col0],  wq1  = Wp[col1];

#pragma unroll
    for (int wm = 0; wm < WM; ++wm) {
#pragma unroll
        for (int r = 0; r < 4; ++r) {
            float v0 = fmaxf(acc[wm][0][r] + b0, 0.0f);
            float v1 = fmaxf(acc[wm][1][r] + b1, 0.0f);
            v0 = bf2f(f2bf(v0));   // match the previous bf16 round-trip of xt
            v1 = bf2f(f2bf(v1));
            float spi = v0 * wpi0 + v1 * wpi1;
            float sn  = v0 * wn0  + v1 * wn1;
            float sp  = v0 * wq0  + v1 * wq1;
#pragma unroll
            for (int m = 1; m < 16; m <<= 1) {
                spi += __shfl_xor(spi, m);
                sn  += __shfl_xor(sn, m);
                sp  += __shfl_xor(sp, m);
            }
            if (l16 == 0) {
                int row = wm * 16 + q * 4 + r;
                part[w][0][row] = spi;
                part[w][1][row] = sn;
                part[w][2][row] = sp;
            }
        }
    }
    __syncthreads();
    if (threadIdx.x < 192) {
        int h = threadIdx.x >> 6;
        int row = threadIdx.x & 63;
        float s = part[0][h][row] + part[1][h][row] + part[2][h][row] + part[3][h][row];
        float bb = (h == 0) ? bpi[0] : (h == 1) ? bn[0] : bp[0];
        float z = s + bb;
        float o;
        if (h == 1) o = (z > 20.0f) ? z : log1pf(expf(z));
        else        o = 1.0f / (1.0f + expf(-z));
        out[h * TOT + R0 + row] = o;
    }
}

extern "C" void kernel_launch(void* const* d_in, const int* in_sizes, int n_in,
                              void* d_out, int out_size, void* d_ws, size_t ws_size,
                              hipStream_t stream) {
    const float* x   = (const float*)d_in[0];
    const int*   ei  = (const int*)d_in[1];
    const int*   src = ei;
    const int*   dst = ei + NE;
    const float* W1 = (const float*)d_in[3];
    const float* b1 = (const float*)d_in[4];
    const float* W2 = (const float*)d_in[5];
    const float* b2 = (const float*)d_in[6];
    const float* W3 = (const float*)d_in[7];
    const float* b3 = (const float*)d_in[8];
    const float* tW1 = (const float*)d_in[9];
    const float* tb1 = (const float*)d_in[10];
    const float* tW2 = (const float*)d_in[11];
    const float* tb2 = (const float*)d_in[12];
    const float* tW3 = (const float*)d_in[13];
    const float* tb3 = (const float*)d_in[14];
    const float* Wpi = (const float*)d_in[15];
    const float* bpi = (const float*)d_in[16];
    const float* Wn  = (const float*)d_in[17];
    const float* bn  = (const float*)d_in[18];
    const float* Wp  = (const float*)d_in[19];
    const float* bp  = (const float*)d_in[20];

    // ---- workspace layout ----
    char* ws = (char*)d_ws;
    float* dinv = (float*)(ws + (0ull << 20));            // 512 KB
    int*   head = (int*)  (ws + (1ull << 20));            // 512 KB
    int2*  nodes = (int2*)(ws + (2ull << 20));            // 8 MB
    unsigned short* wpG1 = (unsigned short*)(ws + (10ull << 20));
    unsigned short* wpG2 = (unsigned short*)(ws + (10ull << 20) + (128 << 10));
    unsigned short* wpG3 = (unsigned short*)(ws + (10ull << 20) + (256 << 10));
    unsigned short* wpC1 = (unsigned short*)(ws + (10ull << 20) + (384 << 10));
    unsigned short* wpC2 = (unsigned short*)(ws + (10ull << 20) + (512 << 10));
    unsigned short* wpC3 = (unsigned short*)(ws + (10ull << 20) + (640 << 10));
    unsigned short* Xa = (unsigned short*)(ws + (16ull  << 20));  // 64ch  16.8 MB
    unsigned short* Xb = (unsigned short*)(ws + (36ull  << 20));  // 128ch 33.6 MB
    unsigned short* Xc = (unsigned short*)(ws + (72ull  << 20));  // 128ch 33.6 MB
    unsigned short* Xd = (unsigned short*)(ws + (108ull << 20));  // 32ch   8.4 MB
    unsigned short* Xe = (unsigned short*)(ws + (120ull << 20));  // 32ch   8.4 MB

    // ---- prep ----
    hipMemsetAsync(head, 0xFF, TOT * sizeof(int), stream);
    k_packall<<<352, 256, 0, stream>>>(W1, W2, W3, tW1, tW2, tW3,
                                       wpG1, wpG2, wpG3, wpC1, wpC2, wpC3);

    // ---- adjacency (linked list, 8-way ILP) + fused deg/dinv/scale ----
    k_link<<<512, 256, 0, stream>>>(src, dst, head, nodes);
    k_prep<<<TOT * 8 / 256, 256, 0, stream>>>((const float4*)x, head, nodes, dinv, (uint4*)Xa);

    // ---- GCN layer 1 ----
    k_gatherb<3, 2><<<TOT * 8 / 256, 256, 0, stream>>>((const uint4*)Xa, head, nodes, dinv,
                                                       nullptr, (uint4*)Xb);
    k_mm<64, 128, 1, true, true, false>
        <<<TOT / 64, 256, 0, stream>>>(Xb, (const bf16x8*)wpG1, b1, dinv, Xc);

    // ---- GCN layer 2 ----
    k_mm<128, 32, 1, false, false, true>
        <<<TOT / 64, 256, 0, stream>>>(Xc, (const bf16x8*)wpG2, nullptr, dinv, Xd);
    k_gatherb<2, 1><<<TOT * 4 / 256, 256, 0, stream>>>((const uint4*)Xd, head, nodes, dinv,
                                                       b2, (uint4*)Xe);

    // ---- GCN layer 3 ----
    k_gatherb<2, 2><<<TOT * 4 / 256, 256, 0, stream>>>((const uint4*)Xe, head, nodes, dinv,
                                                       nullptr, (uint4*)Xd);
    k_mm<32, 128, 1, true, true, false>
        <<<TOT / 64, 256, 0, stream>>>(Xd, (const bf16x8*)wpG3, b3, dinv, Xb);

    // ---- temporal convs 1,2 ----
    k_mm<128, 128, 3, true, true, false>
        <<<TOT / 64, 256, 0, stream>>>(Xb, (const bf16x8*)wpC1, tb1, nullptr, Xc);
    k_mm<128, 32, 3, true, true, false>
        <<<TOT / 64, 256, 0, stream>>>(Xc, (const bf16x8*)wpC2, tb2, nullptr, Xd);

    // ---- conv3 + heads fused (xt never materialized) ----
    k_conv_heads<<<TOT / 64, 256, 0, stream>>>(Xd, (const bf16x8*)wpC3, tb3,
                                               Wpi, bpi, Wn, bn, Wp, bp, (float*)d_out);
}